// Round 1
// baseline (1362.977 us; speedup 1.0000x reference)
//
#include <hip/hip_runtime.h>
#include <hip/hip_bf16.h>

#define S_LEN 2048
#define HID 2048
#define NH 32
#define NKV 8
#define HD 64
#define DQKV 3072          // 2048 (q) + 512 (k) + 512 (v)
#define K_OFF 2048
#define V_OFF 2560
#define SCALE 0.125f

// ---------------- generic fp32 GEMM: C[M][N] = A[M][K] @ B[K][N] ----------------
// grid (N/64, M/64), block 256; each thread computes 4x4.
__global__ void gemm_f32(const float* __restrict__ A, const float* __restrict__ B,
                         float* __restrict__ C, int K, int lda, int ldb, int ldc) {
    __shared__ float As[16][64];   // [k][m]  (K-major so frag reads are float4)
    __shared__ float Bs[16][64];   // [k][n]
    const int t = threadIdx.x;
    const int m0 = blockIdx.y * 64, n0 = blockIdx.x * 64;
    const int tx = t & 15, ty = t >> 4;
    const int a_m = t & 63, a_k4 = (t >> 6) << 2;
    const int b_n4 = (t & 15) << 2, b_k = t >> 4;
    float acc[4][4] = {};
    for (int k0 = 0; k0 < K; k0 += 16) {
        float4 av = *(const float4*)&A[(size_t)(m0 + a_m) * lda + k0 + a_k4];
        float4 bv = *(const float4*)&B[(size_t)(k0 + b_k) * ldb + n0 + b_n4];
        __syncthreads();
        As[a_k4 + 0][a_m] = av.x; As[a_k4 + 1][a_m] = av.y;
        As[a_k4 + 2][a_m] = av.z; As[a_k4 + 3][a_m] = av.w;
        *(float4*)&Bs[b_k][b_n4] = bv;
        __syncthreads();
#pragma unroll
        for (int kk = 0; kk < 16; ++kk) {
            float4 a4 = *(const float4*)&As[kk][ty << 2];
            float4 b4 = *(const float4*)&Bs[kk][tx << 2];
            float a_[4] = {a4.x, a4.y, a4.z, a4.w};
            float b_[4] = {b4.x, b4.y, b4.z, b4.w};
#pragma unroll
            for (int i = 0; i < 4; ++i)
#pragma unroll
                for (int j = 0; j < 4; ++j)
                    acc[i][j] = fmaf(a_[i], b_[j], acc[i][j]);
        }
    }
#pragma unroll
    for (int i = 0; i < 4; ++i) {
        float4 o = {acc[i][0], acc[i][1], acc[i][2], acc[i][3]};
        *(float4*)&C[(size_t)(m0 + (ty << 2) + i) * ldc + n0 + (tx << 2)] = o;
    }
}

// ---------------- RoPE in place on q and k columns of qkv ----------------
// one thread per (s, head<40, pair d<32); head<32 -> q, else k head-32
__global__ void rope_kernel(float* __restrict__ qkv, const float* __restrict__ cosb,
                            const float* __restrict__ sinb) {
    int idx = blockIdx.x * blockDim.x + threadIdx.x;
    int d = idx & 31;
    int head = (idx >> 5) % 40;
    int s = idx / (32 * 40);
    if (s >= S_LEN) return;
    float c1 = cosb[s * HD + d],      s1 = sinb[s * HD + d];
    float c2 = cosb[s * HD + d + 32], s2 = sinb[s * HD + d + 32];
    int col = (head < NH) ? head * HD + d : K_OFF + (head - NH) * HD + d;
    float* p = qkv + (size_t)s * DQKV + col;
    float x1 = p[0], x2 = p[32];
    p[0]  = x1 * c1 - x2 * s1;
    p[32] = x2 * c2 + x1 * s2;
}

// ---------------- scores: raw q.k*scale into weights (lower-tri 64x64 tiles) ----
// grid (32 kt, 32 qt, 32 h), block 256
__global__ void scores_kernel(const float* __restrict__ qkv, float* __restrict__ w) {
    const int kt = blockIdx.x, qt = blockIdx.y, h = blockIdx.z;
    if (kt > qt) return;
    __shared__ float Qs[64][64];   // [d][qrow]
    __shared__ float Ks[64][64];   // [d][krow]
    const int t = threadIdx.x;
    const int row = t & 63;
    const int kvh = h >> 2;
    const float* qbase = qkv + (size_t)(qt * 64) * DQKV + h * HD;
    const float* kbase = qkv + (size_t)(kt * 64) * DQKV + K_OFF + kvh * HD;
#pragma unroll
    for (int p = 0; p < 4; ++p) {
        int d4 = ((t >> 6) << 2) + (p << 4);
        float4 qv = *(const float4*)&qbase[(size_t)row * DQKV + d4];
        float4 kv = *(const float4*)&kbase[(size_t)row * DQKV + d4];
        Qs[d4 + 0][row] = qv.x; Qs[d4 + 1][row] = qv.y;
        Qs[d4 + 2][row] = qv.z; Qs[d4 + 3][row] = qv.w;
        Ks[d4 + 0][row] = kv.x; Ks[d4 + 1][row] = kv.y;
        Ks[d4 + 2][row] = kv.z; Ks[d4 + 3][row] = kv.w;
    }
    __syncthreads();
    const int tx = t & 15, ty = t >> 4;
    float acc[4][4] = {};
#pragma unroll 8
    for (int d = 0; d < 64; ++d) {
        float4 a4 = *(const float4*)&Qs[d][ty << 2];
        float4 b4 = *(const float4*)&Ks[d][tx << 2];
        float a_[4] = {a4.x, a4.y, a4.z, a4.w};
        float b_[4] = {b4.x, b4.y, b4.z, b4.w};
#pragma unroll
        for (int i = 0; i < 4; ++i)
#pragma unroll
            for (int j = 0; j < 4; ++j)
                acc[i][j] = fmaf(a_[i], b_[j], acc[i][j]);
    }
    const int q0 = qt * 64, k0 = kt * 64;
#pragma unroll
    for (int i = 0; i < 4; ++i) {
        int qi = q0 + (ty << 2) + i;
        float4 o = {acc[i][0] * SCALE, acc[i][1] * SCALE,
                    acc[i][2] * SCALE, acc[i][3] * SCALE};
        *(float4*)&w[((size_t)h * S_LEN + qi) * S_LEN + k0 + (tx << 2)] = o;
    }
}

// ---------------- row softmax in place; zero-fills masked tail -------------------
// grid NH*S blocks, block 256
__global__ void softmax_kernel(float* __restrict__ w) {
    __shared__ float buf[S_LEN];
    __shared__ float red[4];
    const int t = threadIdx.x;
    const int qi = blockIdx.x & (S_LEN - 1);
    const int h = blockIdx.x >> 11;
    float* row = w + ((size_t)h * S_LEN + qi) * S_LEN;
    const int L = qi + 1;
    float m = -3.4e38f;
    for (int k = t; k < L; k += 256) { float x = row[k]; buf[k] = x; m = fmaxf(m, x); }
#pragma unroll
    for (int o = 32; o; o >>= 1) m = fmaxf(m, __shfl_xor(m, o));
    if ((t & 63) == 0) red[t >> 6] = m;
    __syncthreads();
    m = fmaxf(fmaxf(red[0], red[1]), fmaxf(red[2], red[3]));
    __syncthreads();
    float sum = 0.f;
    for (int k = t; k < L; k += 256) { float e = __expf(buf[k] - m); buf[k] = e; sum += e; }
#pragma unroll
    for (int o = 32; o; o >>= 1) sum += __shfl_xor(sum, o);
    if ((t & 63) == 0) red[t >> 6] = sum;
    __syncthreads();
    sum = red[0] + red[1] + red[2] + red[3];
    float inv = 1.0f / sum;
    for (int k = t; k < S_LEN; k += 256) row[k] = (k < L) ? buf[k] * inv : 0.0f;
}

// ---------------- PV: attn = weights @ V, written into dead q-columns of qkv -----
// grid (32 qt, 32 h), block 256
__global__ void pv_kernel(const float* __restrict__ w, float* __restrict__ qkv) {
    __shared__ float Ws[16][64];   // [k][qrow]
    __shared__ float Vs[16][64];   // [k][d]
    const int qt = blockIdx.x, h = blockIdx.y;
    const int t = threadIdx.x;
    const int kvh = h >> 2;
    const float* wrow = w + ((size_t)h * S_LEN + qt * 64) * S_LEN;
    const float* vbase = qkv + V_OFF + kvh * HD;
    const int tx = t & 15, ty = t >> 4;
    const int a_m = t & 63, a_k4 = (t >> 6) << 2;
    const int b_n4 = (t & 15) << 2, b_k = t >> 4;
    float acc[4][4] = {};
    const int kmax = (qt + 1) * 64;
    for (int k0 = 0; k0 < kmax; k0 += 16) {
        float4 av = *(const float4*)&wrow[(size_t)a_m * S_LEN + k0 + a_k4];
        float4 bv = *(const float4*)&vbase[(size_t)(k0 + b_k) * DQKV + b_n4];
        __syncthreads();
        Ws[a_k4 + 0][a_m] = av.x; Ws[a_k4 + 1][a_m] = av.y;
        Ws[a_k4 + 2][a_m] = av.z; Ws[a_k4 + 3][a_m] = av.w;
        *(float4*)&Vs[b_k][b_n4] = bv;
        __syncthreads();
#pragma unroll
        for (int kk = 0; kk < 16; ++kk) {
            float4 a4 = *(const float4*)&Ws[kk][ty << 2];
            float4 b4 = *(const float4*)&Vs[kk][tx << 2];
            float a_[4] = {a4.x, a4.y, a4.z, a4.w};
            float b_[4] = {b4.x, b4.y, b4.z, b4.w};
#pragma unroll
            for (int i = 0; i < 4; ++i)
#pragma unroll
                for (int j = 0; j < 4; ++j)
                    acc[i][j] = fmaf(a_[i], b_[j], acc[i][j]);
        }
    }
    float* out = qkv + (size_t)(qt * 64) * DQKV + h * HD;
#pragma unroll
    for (int i = 0; i < 4; ++i) {
        float4 o = {acc[i][0], acc[i][1], acc[i][2], acc[i][3]};
        *(float4*)&out[(size_t)((ty << 2) + i) * DQKV + (tx << 2)] = o;
    }
}

extern "C" void kernel_launch(void* const* d_in, const int* in_sizes, int n_in,
                              void* d_out, int out_size, void* d_ws, size_t ws_size,
                              hipStream_t stream) {
    const float* hidden = (const float*)d_in[0];
    const float* cosb   = (const float*)d_in[1];
    const float* sinb   = (const float*)d_in[2];
    const float* Wq     = (const float*)d_in[3];
    const float* Wk     = (const float*)d_in[4];
    const float* Wv     = (const float*)d_in[5];
    const float* Wo     = (const float*)d_in[6];

    float* out_mat = (float*)d_out;                              // S x HID
    float* weights = (float*)d_out + (size_t)S_LEN * HID;        // NH x S x S
    float* qkv     = (float*)d_ws;                               // S x DQKV (24 MB)

    // 1) QKV projections
    gemm_f32<<<dim3(HID / 64, S_LEN / 64), 256, 0, stream>>>(hidden, Wq, qkv,          HID, HID, HID, DQKV);
    gemm_f32<<<dim3(512 / 64, S_LEN / 64), 256, 0, stream>>>(hidden, Wk, qkv + K_OFF,  HID, HID, 512, DQKV);
    gemm_f32<<<dim3(512 / 64, S_LEN / 64), 256, 0, stream>>>(hidden, Wv, qkv + V_OFF,  HID, HID, 512, DQKV);

    // 2) RoPE on q and k
    {
        int total = S_LEN * 40 * 32;
        rope_kernel<<<total / 256, 256, 0, stream>>>(qkv, cosb, sinb);
    }

    // 3) raw scores (lower triangle)
    scores_kernel<<<dim3(32, 32, NH), 256, 0, stream>>>(qkv, weights);

    // 4) softmax rows (writes full S-wide rows incl. causal zeros)
    softmax_kernel<<<NH * S_LEN, 256, 0, stream>>>(weights);

    // 5) PV into dead q-columns of qkv
    pv_kernel<<<dim3(32, NH), 256, 0, stream>>>(weights, qkv);

    // 6) output projection
    gemm_f32<<<dim3(HID / 64, S_LEN / 64), 256, 0, stream>>>(qkv, Wo, out_mat, HID, DQKV, HID, HID);
}

// Round 2
// 617.278 us; speedup vs baseline: 2.2080x; 2.2080x over previous
//
#include <hip/hip_runtime.h>

typedef short short8 __attribute__((ext_vector_type(8)));
typedef float f32x4 __attribute__((ext_vector_type(4)));

#define S_LEN 2048
#define HID 2048
#define NH 32
#define NKV 8
#define HD 64
#define DQKV 3072
#define K_OFF 2048
#define V_OFF 2560
#define SCALE 0.125f
#define LDP 72   // padded LDS leading dim (bf16 elems): 144B rows -> conflict-free-ish

static __device__ __forceinline__ unsigned short f2bf(float f) {
    unsigned int u = __float_as_uint(f);
    u += 0x7FFF + ((u >> 16) & 1);          // round-to-nearest-even
    return (unsigned short)(u >> 16);
}

// ---------- transpose + convert: dst[c][r] (bf16, ld=dld) = src[r][c] (f32, ld=sld)
// grid (cols/32, rows/32), block 256
__global__ void tconv(const float* __restrict__ src, int sld,
                      unsigned short* __restrict__ dst, int dld) {
    __shared__ float tile[32][33];
    const int t = threadIdx.x;
    const int tx = t & 31, ty = t >> 5;
    const int r0 = blockIdx.y * 32, c0 = blockIdx.x * 32;
#pragma unroll
    for (int i = 0; i < 4; ++i)
        tile[ty * 4 + i][tx] = src[(size_t)(r0 + ty * 4 + i) * sld + c0 + tx];
    __syncthreads();
#pragma unroll
    for (int i = 0; i < 4; ++i)
        dst[(size_t)(c0 + ty * 4 + i) * dld + r0 + tx] = f2bf(tile[tx][ty * 4 + i]);
}

// ---------- strided convert f32 -> bf16 (row stride sld -> dense cols)
__global__ void conv_strided(const float* __restrict__ src, int sld,
                             unsigned short* __restrict__ dst, int cols) {
    int idx = blockIdx.x * 256 + threadIdx.x;       // one float4 per thread
    int c4 = cols >> 2;
    int row = idx / c4, c = (idx - row * c4) * 4;
    if (row >= S_LEN) return;
    float4 v = *(const float4*)&src[(size_t)row * sld + c];
    ushort4 o = {f2bf(v.x), f2bf(v.y), f2bf(v.z), f2bf(v.w)};
    *(ushort4*)&dst[(size_t)row * cols + c] = o;
}

// ---------- MFMA GEMM: C[M][N] f32 = A[M][K] f32 @ Bt[N][K] bf16
// grid (N/128, M/128), block 256 (4 waves, each 64x64)
__global__ void gemm_bf16(const float* __restrict__ A, const unsigned short* __restrict__ Bt,
                          float* __restrict__ C, int K, int lda, int ldb, int ldc) {
    __shared__ __align__(16) unsigned short As[128 * LDP];
    __shared__ __align__(16) unsigned short Bs[128 * LDP];
    const int t = threadIdx.x;
    const int m0 = blockIdx.y * 128, n0 = blockIdx.x * 128;
    const int lane = t & 63, w = t >> 6;
    const int wm = w >> 1, wn = w & 1;
    const int r_st = t >> 3;          // 0..31
    const int c_st = (t & 7) * 8;     // 0..56
    f32x4 acc[4][4] = {};
    for (int k0 = 0; k0 < K; k0 += 64) {
        __syncthreads();
#pragma unroll
        for (int p = 0; p < 4; ++p) {
            int row = r_st + p * 32;
            float4 a0 = *(const float4*)&A[(size_t)(m0 + row) * lda + k0 + c_st];
            float4 a1 = *(const float4*)&A[(size_t)(m0 + row) * lda + k0 + c_st + 4];
            ushort4 lo = {f2bf(a0.x), f2bf(a0.y), f2bf(a0.z), f2bf(a0.w)};
            ushort4 hi = {f2bf(a1.x), f2bf(a1.y), f2bf(a1.z), f2bf(a1.w)};
            *(ushort4*)&As[row * LDP + c_st] = lo;
            *(ushort4*)&As[row * LDP + c_st + 4] = hi;
            short8 bv = *(const short8*)&Bt[(size_t)(n0 + row) * ldb + k0 + c_st];
            *(short8*)&Bs[row * LDP + c_st] = bv;
        }
        __syncthreads();
#pragma unroll
        for (int kk = 0; kk < 64; kk += 32) {
            short8 a[4], b[4];
#pragma unroll
            for (int i = 0; i < 4; ++i)
                a[i] = *(const short8*)&As[(wm * 64 + i * 16 + (lane & 15)) * LDP + kk + (lane >> 4) * 8];
#pragma unroll
            for (int j = 0; j < 4; ++j)
                b[j] = *(const short8*)&Bs[(wn * 64 + j * 16 + (lane & 15)) * LDP + kk + (lane >> 4) * 8];
#pragma unroll
            for (int i = 0; i < 4; ++i)
#pragma unroll
                for (int j = 0; j < 4; ++j)
                    acc[i][j] = __builtin_amdgcn_mfma_f32_16x16x32_bf16(a[i], b[j], acc[i][j], 0, 0, 0);
        }
    }
#pragma unroll
    for (int i = 0; i < 4; ++i)
#pragma unroll
        for (int j = 0; j < 4; ++j)
#pragma unroll
            for (int r = 0; r < 4; ++r)
                C[(size_t)(m0 + wm * 64 + i * 16 + (lane >> 4) * 4 + r) * ldc +
                  n0 + wn * 64 + j * 16 + (lane & 15)] = acc[i][j][r];
}

// ---------- RoPE in place on q and k columns of qkv (fp32)
__global__ void rope_kernel(float* __restrict__ qkv, const float* __restrict__ cosb,
                            const float* __restrict__ sinb) {
    int idx = blockIdx.x * blockDim.x + threadIdx.x;
    int d = idx & 31;
    int head = (idx >> 5) % 40;
    int s = idx / (32 * 40);
    if (s >= S_LEN) return;
    float c1 = cosb[s * HD + d],      s1 = sinb[s * HD + d];
    float c2 = cosb[s * HD + d + 32], s2 = sinb[s * HD + d + 32];
    int col = (head < NH) ? head * HD + d : K_OFF + (head - NH) * HD + d;
    float* p = qkv + (size_t)s * DQKV + col;
    float x1 = p[0], x2 = p[32];
    p[0]  = x1 * c1 - x2 * s1;
    p[32] = x2 * c2 + x1 * s2;
}

// ---------- scores (MFMA, direct global frags): w = scale * Q K^T, lower 128-tiles
// grid (16 kt, 16 qt, 32 h), block 256
__global__ void scores_mfma(const unsigned short* __restrict__ Qb,
                            const unsigned short* __restrict__ Kb,
                            float* __restrict__ w) {
    const int kt = blockIdx.x, qt = blockIdx.y, h = blockIdx.z;
    if (kt > qt) return;
    const int t = threadIdx.x, lane = t & 63, wv = t >> 6;
    const int wm = wv >> 1, wn = wv & 1;
    const int q0 = qt * 128, k0s = kt * 128, kvh = h >> 2;
    f32x4 acc[4][4] = {};
#pragma unroll
    for (int kk = 0; kk < 64; kk += 32) {
        short8 a[4], b[4];
#pragma unroll
        for (int i = 0; i < 4; ++i)
            a[i] = *(const short8*)&Qb[(size_t)(q0 + wm * 64 + i * 16 + (lane & 15)) * HID +
                                       h * HD + kk + (lane >> 4) * 8];
#pragma unroll
        for (int j = 0; j < 4; ++j)
            b[j] = *(const short8*)&Kb[(size_t)(k0s + wn * 64 + j * 16 + (lane & 15)) * 512 +
                                       kvh * HD + kk + (lane >> 4) * 8];
#pragma unroll
        for (int i = 0; i < 4; ++i)
#pragma unroll
            for (int j = 0; j < 4; ++j)
                acc[i][j] = __builtin_amdgcn_mfma_f32_16x16x32_bf16(a[i], b[j], acc[i][j], 0, 0, 0);
    }
#pragma unroll
    for (int i = 0; i < 4; ++i)
#pragma unroll
        for (int j = 0; j < 4; ++j)
#pragma unroll
            for (int r = 0; r < 4; ++r)
                w[((size_t)h * S_LEN + q0 + wm * 64 + i * 16 + (lane >> 4) * 4 + r) * S_LEN +
                  k0s + wn * 64 + j * 16 + (lane & 15)] = acc[i][j][r] * SCALE;
}

// ---------- row softmax in place; zero-fills masked tail
__global__ void softmax_kernel(float* __restrict__ w) {
    __shared__ float buf[S_LEN];
    __shared__ float red[4];
    const int t = threadIdx.x;
    const int qi = blockIdx.x & (S_LEN - 1);
    const int h = blockIdx.x >> 11;
    float* row = w + ((size_t)h * S_LEN + qi) * S_LEN;
    const int L = qi + 1;
    float m = -3.4e38f;
    for (int k = t; k < L; k += 256) { float x = row[k]; buf[k] = x; m = fmaxf(m, x); }
#pragma unroll
    for (int o = 32; o; o >>= 1) m = fmaxf(m, __shfl_xor(m, o));
    if ((t & 63) == 0) red[t >> 6] = m;
    __syncthreads();
    m = fmaxf(fmaxf(red[0], red[1]), fmaxf(red[2], red[3]));
    __syncthreads();
    float sum = 0.f;
    for (int k = t; k < L; k += 256) { float e = __expf(buf[k] - m); buf[k] = e; sum += e; }
#pragma unroll
    for (int o = 32; o; o >>= 1) sum += __shfl_xor(sum, o);
    if ((t & 63) == 0) red[t >> 6] = sum;
    __syncthreads();
    sum = red[0] + red[1] + red[2] + red[3];
    float inv = 1.0f / sum;
    for (int k = t; k < S_LEN; k += 256) row[k] = (k < L) ? buf[k] * inv : 0.0f;
}

// ---------- PV (MFMA): attn[q][d] = sum_k w[q][k] * V[k][d]; writes fp32 into qkv q-cols
// grid (16 qt, 32 h), block 256 (4 waves, each 32 q-rows x 64 d)
__global__ void pv_mfma(const float* __restrict__ w, const unsigned short* __restrict__ Vt,
                        float* __restrict__ qkv) {
    __shared__ __align__(16) unsigned short Ws[128 * LDP];
    const int qt = blockIdx.x, h = blockIdx.y;
    const int t = threadIdx.x, lane = t & 63, wv = t >> 6;
    const int q0 = qt * 128, kvh = h >> 2;
    const int r_st = t >> 4;          // 0..15
    const int c_st = (t & 15) * 4;    // 0..60
    f32x4 acc[2][4] = {};
    const int kmax = (qt + 1) * 128;
    for (int kt = 0; kt < kmax; kt += 64) {
        __syncthreads();
#pragma unroll
        for (int p = 0; p < 8; ++p) {
            int row = r_st + p * 16;
            float4 v = *(const float4*)&w[((size_t)h * S_LEN + q0 + row) * S_LEN + kt + c_st];
            ushort4 b4 = {f2bf(v.x), f2bf(v.y), f2bf(v.z), f2bf(v.w)};
            *(ushort4*)&Ws[row * LDP + c_st] = b4;
        }
        __syncthreads();
#pragma unroll
        for (int kk = 0; kk < 64; kk += 32) {
            short8 a[2], b[4];
#pragma unroll
            for (int i = 0; i < 2; ++i)
                a[i] = *(const short8*)&Ws[(wv * 32 + i * 16 + (lane & 15)) * LDP + kk + (lane >> 4) * 8];
#pragma unroll
            for (int j = 0; j < 4; ++j)
                b[j] = *(const short8*)&Vt[(size_t)(kvh * HD + j * 16 + (lane & 15)) * S_LEN +
                                           kt + kk + (lane >> 4) * 8];
#pragma unroll
            for (int i = 0; i < 2; ++i)
#pragma unroll
                for (int j = 0; j < 4; ++j)
                    acc[i][j] = __builtin_amdgcn_mfma_f32_16x16x32_bf16(a[i], b[j], acc[i][j], 0, 0, 0);
        }
    }
#pragma unroll
    for (int i = 0; i < 2; ++i)
#pragma unroll
        for (int j = 0; j < 4; ++j)
#pragma unroll
            for (int r = 0; r < 4; ++r)
                qkv[(size_t)(q0 + wv * 32 + i * 16 + (lane >> 4) * 4 + r) * DQKV +
                    h * HD + j * 16 + (lane & 15)] = acc[i][j][r];
}

extern "C" void kernel_launch(void* const* d_in, const int* in_sizes, int n_in,
                              void* d_out, int out_size, void* d_ws, size_t ws_size,
                              hipStream_t stream) {
    const float* hidden = (const float*)d_in[0];
    const float* cosb   = (const float*)d_in[1];
    const float* sinb   = (const float*)d_in[2];
    const float* Wq     = (const float*)d_in[3];
    const float* Wk     = (const float*)d_in[4];
    const float* Wv     = (const float*)d_in[5];
    const float* Wo     = (const float*)d_in[6];

    float* out_mat = (float*)d_out;                              // S x HID
    float* weights = (float*)d_out + (size_t)S_LEN * HID;        // NH x S x S

    char* wsb = (char*)d_ws;
    float* qkv = (float*)wsb;                                    // 2048x3072 f32 (24 MB)
    unsigned short* Wt  = (unsigned short*)(wsb + (size_t)S_LEN * DQKV * 4);  // 3072x2048 bf16
    unsigned short* Wot = Wt  + (size_t)DQKV * HID;              // 2048x2048 bf16
    unsigned short* Qb  = Wot + (size_t)HID * HID;               // 2048x2048 bf16
    unsigned short* Kb  = Qb  + (size_t)S_LEN * HID;             // 2048x512 bf16
    unsigned short* Vt  = Kb  + (size_t)S_LEN * 512;             // 512x2048 bf16

    // 1) weight transposes -> bf16 (B^T layout)
    tconv<<<dim3(64, 64), 256, 0, stream>>>(Wq, HID, Wt, HID);
    tconv<<<dim3(16, 64), 256, 0, stream>>>(Wk, 512, Wt + (size_t)K_OFF * HID, HID);
    tconv<<<dim3(16, 64), 256, 0, stream>>>(Wv, 512, Wt + (size_t)V_OFF * HID, HID);
    tconv<<<dim3(64, 64), 256, 0, stream>>>(Wo, HID, Wot, HID);

    // 2) QKV projection (one fused GEMM, N = 3072)
    gemm_bf16<<<dim3(DQKV / 128, S_LEN / 128), 256, 0, stream>>>(hidden, Wt, qkv, HID, HID, HID, DQKV);

    // 3) RoPE on q and k (fp32, in place)
    rope_kernel<<<(S_LEN * 40 * 32) / 256, 256, 0, stream>>>(qkv, cosb, sinb);

    // 4) convert q,k to bf16; transpose v
    conv_strided<<<(S_LEN * HID / 4) / 256, 256, 0, stream>>>(qkv, DQKV, Qb, HID);
    conv_strided<<<(S_LEN * 512 / 4) / 256, 256, 0, stream>>>(qkv + K_OFF, DQKV, Kb, 512);
    tconv<<<dim3(16, 64), 256, 0, stream>>>(qkv + V_OFF, DQKV, Vt, S_LEN);

    // 5) raw scores (lower 128-tiles incl. diagonal garbage above diag)
    scores_mfma<<<dim3(16, 16, NH), 256, 0, stream>>>(Qb, Kb, weights);

    // 6) softmax rows (overwrites everything >= diag with zeros)
    softmax_kernel<<<NH * S_LEN, 256, 0, stream>>>(weights);

    // 7) PV -> attn fp32 into dead q-columns of qkv
    pv_mfma<<<dim3(16, NH), 256, 0, stream>>>(weights, Vt, qkv);

    // 8) output projection
    gemm_bf16<<<dim3(HID / 128, S_LEN / 128), 256, 0, stream>>>(qkv, Wot, out_mat, HID, DQKV, HID, HID);
}

// Round 3
// 394.978 us; speedup vs baseline: 3.4508x; 1.5628x over previous
//
#include <hip/hip_runtime.h>

typedef short short8 __attribute__((ext_vector_type(8)));
typedef float f32x4 __attribute__((ext_vector_type(4)));

#define S_LEN 2048
#define HID 2048
#define NH 32
#define NKV 8
#define HD 64
#define DQKV 3072
#define K_OFF 2048
#define V_OFF 2560
#define SCALE 0.125f

static __device__ __forceinline__ unsigned short f2bf(float f) {
    unsigned int u = __float_as_uint(f);
    u += 0x7FFF + ((u >> 16) & 1);          // RNE
    return (unsigned short)(u >> 16);
}
static __device__ __forceinline__ float bf2f(unsigned short u) {
    return __uint_as_float((unsigned int)u << 16);
}

#define GLDS16(g, l)                                                                     \
    __builtin_amdgcn_global_load_lds((const __attribute__((address_space(1))) unsigned int*)(g), \
                                     (__attribute__((address_space(3))) unsigned int*)(l), 16, 0, 0)

// ---------- transpose + convert: dst[c][r] (bf16) = src[r][c] (f32)
__global__ void tconv(const float* __restrict__ src, int sld,
                      unsigned short* __restrict__ dst, int dld) {
    __shared__ float tile[32][33];
    const int t = threadIdx.x;
    const int tx = t & 31, ty = t >> 5;
    const int r0 = blockIdx.y * 32, c0 = blockIdx.x * 32;
#pragma unroll
    for (int i = 0; i < 4; ++i)
        tile[ty * 4 + i][tx] = src[(size_t)(r0 + ty * 4 + i) * sld + c0 + tx];
    __syncthreads();
#pragma unroll
    for (int i = 0; i < 4; ++i)
        dst[(size_t)(c0 + ty * 4 + i) * dld + r0 + tx] = f2bf(tile[tx][ty * 4 + i]);
}

// ---------- dense convert f32 -> bf16
__global__ void conv_dense(const float* __restrict__ src, unsigned short* __restrict__ dst) {
    int idx = blockIdx.x * 256 + threadIdx.x;
    float4 v = *(const float4*)&src[(size_t)idx * 4];
    ushort4 o = {f2bf(v.x), f2bf(v.y), f2bf(v.z), f2bf(v.w)};
    *(ushort4*)&dst[(size_t)idx * 4] = o;
}

// ---------- m97-style MFMA GEMM: C[M][N] f32 = A[M][K] bf16 @ Bt[N][K] bf16
// grid (N/128, M/128), block 256 (4 waves, each 64x64), BK=64, global_load_lds staging
__global__ void gemm_m97(const unsigned short* __restrict__ A, const unsigned short* __restrict__ Bt,
                         float* __restrict__ C, int K, int lda, int ldb, int ldc) {
    __shared__ __align__(16) unsigned short As[128 * 64];
    __shared__ __align__(16) unsigned short Bs[128 * 64];
    const int t = threadIdx.x, lane = t & 63, w = t >> 6;
    const int m0 = blockIdx.y * 128, n0 = blockIdx.x * 128;
    const int wm = w >> 1, wn = w & 1;
    const int lr = lane & 15, lg = lane >> 4;
    const int srow = lane >> 3;          // 0..7
    const int scol = (lane & 7) * 8;     // element col
    f32x4 acc[4][4] = {};
    for (int k0 = 0; k0 < K; k0 += 64) {
        __syncthreads();
#pragma unroll
        for (int p = 0; p < 4; ++p) {
            int rbase = (w * 4 + p) * 8;
            GLDS16(&A[(size_t)(m0 + rbase + srow) * lda + k0 + scol], &As[rbase * 64]);
            GLDS16(&Bt[(size_t)(n0 + rbase + srow) * ldb + k0 + scol], &Bs[rbase * 64]);
        }
        __syncthreads();
#pragma unroll
        for (int kk = 0; kk < 64; kk += 32) {
            short8 a[4], b[4];
#pragma unroll
            for (int i = 0; i < 4; ++i)
                a[i] = *(const short8*)&As[(wm * 64 + i * 16 + lr) * 64 + kk + lg * 8];
#pragma unroll
            for (int j = 0; j < 4; ++j)
                b[j] = *(const short8*)&Bs[(wn * 64 + j * 16 + lr) * 64 + kk + lg * 8];
#pragma unroll
            for (int i = 0; i < 4; ++i)
#pragma unroll
                for (int j = 0; j < 4; ++j)
                    acc[i][j] = __builtin_amdgcn_mfma_f32_16x16x32_bf16(a[i], b[j], acc[i][j], 0, 0, 0);
        }
    }
#pragma unroll
    for (int i = 0; i < 4; ++i)
#pragma unroll
        for (int j = 0; j < 4; ++j)
#pragma unroll
            for (int r = 0; r < 4; ++r)
                C[(size_t)(m0 + wm * 64 + i * 16 + lg * 4 + r) * ldc +
                  n0 + wn * 64 + j * 16 + lr] = acc[i][j][r];
}

// ---------- RoPE from qkv f32 -> Qb/Kb bf16
__global__ void rope_conv(const float* __restrict__ qkv, const float* __restrict__ cosb,
                          const float* __restrict__ sinb, unsigned short* __restrict__ Qb,
                          unsigned short* __restrict__ Kb) {
    int idx = blockIdx.x * 256 + threadIdx.x;
    int d = idx & 31;
    int head = (idx >> 5) % 40;
    int s = idx / (32 * 40);
    if (s >= S_LEN) return;
    float c1 = cosb[s * HD + d],      s1 = sinb[s * HD + d];
    float c2 = cosb[s * HD + d + 32], s2 = sinb[s * HD + d + 32];
    const float* p;
    unsigned short* o;
    if (head < NH) {
        p = qkv + (size_t)s * DQKV + head * HD + d;
        o = Qb + (size_t)s * HID + head * HD + d;
    } else {
        p = qkv + (size_t)s * DQKV + K_OFF + (head - NH) * HD + d;
        o = Kb + (size_t)s * 512 + (head - NH) * HD + d;
    }
    float x1 = p[0], x2 = p[32];
    o[0]  = f2bf(x1 * c1 - x2 * s1);
    o[32] = f2bf(x2 * c2 + x1 * s2);
}

// ---------- fused flash attention with weights output
// grid (16 qt, 32 h), block 256 (4 waves; wave wv owns q rows wv*32..+32)
__global__ void attn_fused(const unsigned short* __restrict__ Qb,
                           const unsigned short* __restrict__ Kb,
                           const unsigned short* __restrict__ Vt,
                           float* __restrict__ w,
                           unsigned short* __restrict__ Ab) {
    __shared__ __align__(16) unsigned short Ks[128 * 72];   // K tile [k][d], 16B row skew
    __shared__ __align__(16) unsigned short Vs[64 * 136];   // V^T tile [d][k]
    __shared__ __align__(16) unsigned short Ps[128 * 136];  // P tile [q][k]
    const int qt = blockIdx.x, h = blockIdx.y, kvh = h >> 2;
    const int t = threadIdx.x, lane = t & 63, wv = t >> 6;
    const int lr = lane & 15, lg = lane >> 4;
    const int q0 = qt * 128;

    // hoist Q fragments (B-operand): rows q0 + wv*32 + i*16 + lr
    short8 qf[2][2];
#pragma unroll
    for (int i = 0; i < 2; ++i)
#pragma unroll
        for (int kk = 0; kk < 2; ++kk)
            qf[i][kk] = *(const short8*)&Qb[(size_t)(q0 + wv * 32 + i * 16 + lr) * HID +
                                            h * HD + kk * 32 + lg * 8];

    float m_r[2] = {-3.0e38f, -3.0e38f};
    float l_r[2] = {0.f, 0.f};

    const int krow = t >> 1, khalf = (t & 1) * 32;
    const int vrow = t >> 2, vq = (t & 3) * 32;

    // ================= pass 1: row max + row sum =================
    for (int kt = 0; kt <= qt; ++kt) {
        __syncthreads();
#pragma unroll
        for (int mth = 0; mth < 4; ++mth)
            *(short8*)&Ks[krow * 72 + khalf + mth * 8] =
                *(const short8*)&Kb[(size_t)(kt * 128 + krow) * 512 + kvh * 64 + khalf + mth * 8];
        __syncthreads();
        f32x4 acc[8][2] = {};
#pragma unroll
        for (int kk = 0; kk < 2; ++kk) {
            short8 af[8];
#pragma unroll
            for (int j = 0; j < 8; ++j)
                af[j] = *(const short8*)&Ks[(j * 16 + lr) * 72 + kk * 32 + lg * 8];
#pragma unroll
            for (int j = 0; j < 8; ++j)
#pragma unroll
                for (int i = 0; i < 2; ++i)
                    acc[j][i] = __builtin_amdgcn_mfma_f32_16x16x32_bf16(af[j], qf[i][kk], acc[j][i], 0, 0, 0);
        }
#pragma unroll
        for (int i = 0; i < 2; ++i) {
            const int qg = q0 + wv * 32 + i * 16 + lr;
            float tm = -3.0e38f;
#pragma unroll
            for (int j = 0; j < 8; ++j)
#pragma unroll
                for (int r = 0; r < 4; ++r) {
                    int kg = kt * 128 + j * 16 + lg * 4 + r;
                    float s = acc[j][i][r] * SCALE;
                    s = (kg <= qg) ? s : -1.0e30f;
                    acc[j][i][r] = s;
                    tm = fmaxf(tm, s);
                }
            tm = fmaxf(tm, __shfl_xor(tm, 16));
            tm = fmaxf(tm, __shfl_xor(tm, 32));
            float mn = fmaxf(m_r[i], tm);
            float sum = 0.f;
#pragma unroll
            for (int j = 0; j < 8; ++j)
#pragma unroll
                for (int r = 0; r < 4; ++r)
                    sum += __expf(acc[j][i][r] - mn);
            sum += __shfl_xor(sum, 16);
            sum += __shfl_xor(sum, 32);
            l_r[i] = l_r[i] * __expf(m_r[i] - mn) + sum;
            m_r[i] = mn;
        }
    }

    const float invl[2] = {1.f / l_r[0], 1.f / l_r[1]};

    // ================= pass 2: weights write + PV =================
    f32x4 o[2][4] = {};
    for (int kt = 0; kt <= qt; ++kt) {
        __syncthreads();
#pragma unroll
        for (int mth = 0; mth < 4; ++mth)
            *(short8*)&Ks[krow * 72 + khalf + mth * 8] =
                *(const short8*)&Kb[(size_t)(kt * 128 + krow) * 512 + kvh * 64 + khalf + mth * 8];
#pragma unroll
        for (int mth = 0; mth < 4; ++mth)
            *(short8*)&Vs[vrow * 136 + vq + mth * 8] =
                *(const short8*)&Vt[(size_t)(kvh * 64 + vrow) * S_LEN + kt * 128 + vq + mth * 8];
        __syncthreads();
        f32x4 acc[8][2] = {};
#pragma unroll
        for (int kk = 0; kk < 2; ++kk) {
            short8 af[8];
#pragma unroll
            for (int j = 0; j < 8; ++j)
                af[j] = *(const short8*)&Ks[(j * 16 + lr) * 72 + kk * 32 + lg * 8];
#pragma unroll
            for (int j = 0; j < 8; ++j)
#pragma unroll
                for (int i = 0; i < 2; ++i)
                    acc[j][i] = __builtin_amdgcn_mfma_f32_16x16x32_bf16(af[j], qf[i][kk], acc[j][i], 0, 0, 0);
        }
        // softmax -> Ps (bf16, self-owned rows)
#pragma unroll
        for (int i = 0; i < 2; ++i) {
            const int qg = q0 + wv * 32 + i * 16 + lr;
#pragma unroll
            for (int j = 0; j < 8; ++j) {
                ushort4 pk;
#pragma unroll
                for (int r = 0; r < 4; ++r) {
                    int kg = kt * 128 + j * 16 + lg * 4 + r;
                    float s = acc[j][i][r] * SCALE;
                    s = (kg <= qg) ? s : -1.0e30f;
                    float pv = __expf(s - m_r[i]) * invl[i];
                    ((unsigned short*)&pk)[r] = f2bf(pv);
                }
                *(ushort4*)&Ps[(wv * 32 + i * 16 + lr) * 136 + j * 16 + lg * 4] = pk;
            }
        }
        // PV: A-frags from own Ps rows, B-frags from Vs
#pragma unroll
        for (int ks = 0; ks < 4; ++ks) {
            short8 pa[2], vb[4];
#pragma unroll
            for (int i = 0; i < 2; ++i)
                pa[i] = *(const short8*)&Ps[(wv * 32 + i * 16 + lr) * 136 + ks * 32 + lg * 8];
#pragma unroll
            for (int j2 = 0; j2 < 4; ++j2)
                vb[j2] = *(const short8*)&Vs[(j2 * 16 + lr) * 136 + ks * 32 + lg * 8];
#pragma unroll
            for (int i = 0; i < 2; ++i)
#pragma unroll
                for (int j2 = 0; j2 < 4; ++j2)
                    o[i][j2] = __builtin_amdgcn_mfma_f32_16x16x32_bf16(pa[i], vb[j2], o[i][j2], 0, 0, 0);
        }
        // weights global write (f32, coalesced: wave covers 2 rows x 512B per instr)
#pragma unroll
        for (int rr = 0; rr < 16; ++rr) {
            int q = wv * 32 + rr * 2 + (lane >> 5);
            int col = (lane & 31) * 4;
            ushort4 p4 = *(const ushort4*)&Ps[q * 136 + col];
            float4 f4 = {bf2f(p4.x), bf2f(p4.y), bf2f(p4.z), bf2f(p4.w)};
            *(float4*)&w[((size_t)h * S_LEN + q0 + q) * S_LEN + kt * 128 + col] = f4;
        }
    }

    // zero-fill strictly-upper tiles of this block's rows
    {
        float4 z = {0.f, 0.f, 0.f, 0.f};
        for (int kt = qt + 1; kt < 16; ++kt)
#pragma unroll
            for (int rr = 0; rr < 16; ++rr) {
                int q = wv * 32 + rr * 2 + (lane >> 5);
                *(float4*)&w[((size_t)h * S_LEN + q0 + q) * S_LEN + kt * 128 + (lane & 31) * 4] = z;
            }
    }

    // write attn output (bf16, dense [s][h*64+d])
#pragma unroll
    for (int i = 0; i < 2; ++i)
#pragma unroll
        for (int j2 = 0; j2 < 4; ++j2)
#pragma unroll
            for (int r = 0; r < 4; ++r)
                Ab[(size_t)(q0 + wv * 32 + i * 16 + lg * 4 + r) * HID +
                   h * HD + j2 * 16 + lr] = f2bf(o[i][j2][r]);
}

extern "C" void kernel_launch(void* const* d_in, const int* in_sizes, int n_in,
                              void* d_out, int out_size, void* d_ws, size_t ws_size,
                              hipStream_t stream) {
    const float* hidden = (const float*)d_in[0];
    const float* cosb   = (const float*)d_in[1];
    const float* sinb   = (const float*)d_in[2];
    const float* Wq     = (const float*)d_in[3];
    const float* Wk     = (const float*)d_in[4];
    const float* Wv     = (const float*)d_in[5];
    const float* Wo     = (const float*)d_in[6];

    float* out_mat = (float*)d_out;                              // S x HID
    float* weights = (float*)d_out + (size_t)S_LEN * HID;        // NH x S x S

    char* wsb = (char*)d_ws;
    float* qkv          = (float*)wsb;                                        // 24 MB
    unsigned short* Wt  = (unsigned short*)(wsb + (size_t)24 * 1024 * 1024);  // 12 MB
    unsigned short* Wot = (unsigned short*)(wsb + (size_t)36 * 1024 * 1024);  // 8 MB
    unsigned short* Qb  = (unsigned short*)(wsb + (size_t)44 * 1024 * 1024);  // 8 MB
    unsigned short* Kb  = (unsigned short*)(wsb + (size_t)52 * 1024 * 1024);  // 2 MB
    unsigned short* Vt  = (unsigned short*)(wsb + (size_t)54 * 1024 * 1024);  // 2 MB
    unsigned short* Hb  = (unsigned short*)(wsb + (size_t)56 * 1024 * 1024);  // 8 MB
    unsigned short* Ab  = Hb;  // alias: Hb dead after QKV GEMM

    // 1) convert hidden -> bf16; weights -> transposed bf16
    conv_dense<<<(S_LEN * HID / 4) / 256, 256, 0, stream>>>(hidden, Hb);
    tconv<<<dim3(64, 64), 256, 0, stream>>>(Wq, HID, Wt, HID);
    tconv<<<dim3(16, 64), 256, 0, stream>>>(Wk, 512, Wt + (size_t)K_OFF * HID, HID);
    tconv<<<dim3(16, 64), 256, 0, stream>>>(Wv, 512, Wt + (size_t)V_OFF * HID, HID);
    tconv<<<dim3(64, 64), 256, 0, stream>>>(Wo, HID, Wot, HID);

    // 2) fused QKV projection
    gemm_m97<<<dim3(DQKV / 128, S_LEN / 128), 256, 0, stream>>>(Hb, Wt, qkv, HID, HID, HID, DQKV);

    // 3) RoPE -> Qb/Kb bf16; V -> Vt (transposed bf16)
    rope_conv<<<(S_LEN * 40 * 32) / 256, 256, 0, stream>>>(qkv, cosb, sinb, Qb, Kb);
    tconv<<<dim3(16, 64), 256, 0, stream>>>(qkv + V_OFF, DQKV, Vt, S_LEN);

    // 4) fused attention: weights (f32) + attn (bf16)
    attn_fused<<<dim3(16, NH), 256, 0, stream>>>(Qb, Kb, Vt, weights, Ab);

    // 5) output projection
    gemm_m97<<<dim3(HID / 128, S_LEN / 128), 256, 0, stream>>>(Ab, Wot, out_mat, HID, HID, HID, HID);
}

// Round 4
// 284.923 us; speedup vs baseline: 4.7837x; 1.3863x over previous
//
#include <hip/hip_runtime.h>

typedef short short8 __attribute__((ext_vector_type(8)));
typedef float f32x4 __attribute__((ext_vector_type(4)));

#define S_LEN 2048
#define HID 2048
#define NH 32
#define NKV 8
#define HD 64
#define DQKV 3072
#define K_OFF 2048
#define V_OFF 2560
#define SCALE 0.125f

static __device__ __forceinline__ unsigned short f2bf(float f) {
    unsigned int u = __float_as_uint(f);
    u += 0x7FFF + ((u >> 16) & 1);          // RNE
    return (unsigned short)(u >> 16);
}
static __device__ __forceinline__ float bf2f(unsigned short u) {
    return __uint_as_float((unsigned int)u << 16);
}

#define GLDS16(g, l)                                                                     \
    __builtin_amdgcn_global_load_lds((const __attribute__((address_space(1))) unsigned int*)(g), \
                                     (__attribute__((address_space(3))) unsigned int*)(l), 16, 0, 0)

// ---------- prep: z<4 -> transpose+convert weights; z==4 -> convert hidden to bf16
// grid (64, 64, 5), block 256
__global__ void prep(const float* __restrict__ Wq, const float* __restrict__ Wk,
                     const float* __restrict__ Wv, const float* __restrict__ Wo,
                     const float* __restrict__ hidden,
                     unsigned short* __restrict__ Wt, unsigned short* __restrict__ Wot,
                     unsigned short* __restrict__ Hb) {
    const int z = blockIdx.z;
    const int t = threadIdx.x;
    if (z == 4) {
        int idx = (blockIdx.y * 64 + blockIdx.x) * 256 + t;
        float4 v = ((const float4*)hidden)[idx];
        ushort4 o = {f2bf(v.x), f2bf(v.y), f2bf(v.z), f2bf(v.w)};
        ((ushort4*)Hb)[idx] = o;
        return;
    }
    const float* src; unsigned short* dst; int sld;
    if (z == 0)      { src = Wq; dst = Wt; sld = HID; }
    else if (z == 1) { if (blockIdx.x >= 16) return; src = Wk; dst = Wt + (size_t)K_OFF * HID; sld = 512; }
    else if (z == 2) { if (blockIdx.x >= 16) return; src = Wv; dst = Wt + (size_t)V_OFF * HID; sld = 512; }
    else             { src = Wo; dst = Wot; sld = HID; }
    __shared__ float tile[32][33];
    const int tx = t & 31, ty = t >> 5;
    const int r0 = blockIdx.y * 32, c0 = blockIdx.x * 32;
#pragma unroll
    for (int i = 0; i < 4; ++i)
        tile[ty * 4 + i][tx] = src[(size_t)(r0 + ty * 4 + i) * sld + c0 + tx];
    __syncthreads();
#pragma unroll
    for (int i = 0; i < 4; ++i)
        dst[(size_t)(c0 + ty * 4 + i) * HID + r0 + tx] = f2bf(tile[tx][ty * 4 + i]);
}

// ---------- transpose + convert (for V^T): dst[c][r] (bf16) = src[r][c] (f32)
__global__ void tconv(const float* __restrict__ src, int sld,
                      unsigned short* __restrict__ dst, int dld) {
    __shared__ float tile[32][33];
    const int t = threadIdx.x;
    const int tx = t & 31, ty = t >> 5;
    const int r0 = blockIdx.y * 32, c0 = blockIdx.x * 32;
#pragma unroll
    for (int i = 0; i < 4; ++i)
        tile[ty * 4 + i][tx] = src[(size_t)(r0 + ty * 4 + i) * sld + c0 + tx];
    __syncthreads();
#pragma unroll
    for (int i = 0; i < 4; ++i)
        dst[(size_t)(c0 + ty * 4 + i) * dld + r0 + tx] = f2bf(tile[tx][ty * 4 + i]);
}

// ---------- 8-wave MFMA GEMM: C[M][N] f32 = A[M][K] bf16 @ Bt[N][K] bf16
// grid (N/128, M/128), block 512 (8 waves, each 32x64), BK=64, global_load_lds + XOR swizzle
__global__ __launch_bounds__(512) void gemm_m97(const unsigned short* __restrict__ A,
                                                const unsigned short* __restrict__ Bt,
                                                float* __restrict__ C, int K, int lda, int ldb, int ldc) {
    __shared__ __align__(16) unsigned short As[128 * 64];
    __shared__ __align__(16) unsigned short Bs[128 * 64];
    const int t = threadIdx.x, lane = t & 63, wv = t >> 6;
    const int m0 = blockIdx.y * 128, n0 = blockIdx.x * 128;
    const int wm = wv >> 1, wn = wv & 1;
    const int lr = lane & 15, lg = lane >> 4;
    const int srow = lane >> 3;                              // 0..7 within 8-row group
    const int scol = ((lane & 7) ^ srow) * 8;                // pre-swizzled global col
    f32x4 acc[2][4] = {};
    for (int k0 = 0; k0 < K; k0 += 64) {
        __syncthreads();
#pragma unroll
        for (int p = 0; p < 2; ++p) {
            int rbase = wv * 16 + p * 8;
            GLDS16(&A[(size_t)(m0 + rbase + srow) * lda + k0 + scol], &As[rbase * 64]);
            GLDS16(&Bt[(size_t)(n0 + rbase + srow) * ldb + k0 + scol], &Bs[rbase * 64]);
        }
        __syncthreads();
#pragma unroll
        for (int kk = 0; kk < 2; ++kk) {
            short8 a[2], b[4];
#pragma unroll
            for (int i = 0; i < 2; ++i) {
                int row = wm * 32 + i * 16 + lr;
                a[i] = *(const short8*)&As[row * 64 + (((kk * 4 + lg) ^ (row & 7)) * 8)];
            }
#pragma unroll
            for (int j = 0; j < 4; ++j) {
                int row = wn * 64 + j * 16 + lr;
                b[j] = *(const short8*)&Bs[row * 64 + (((kk * 4 + lg) ^ (row & 7)) * 8)];
            }
#pragma unroll
            for (int i = 0; i < 2; ++i)
#pragma unroll
                for (int j = 0; j < 4; ++j)
                    acc[i][j] = __builtin_amdgcn_mfma_f32_16x16x32_bf16(a[i], b[j], acc[i][j], 0, 0, 0);
        }
    }
#pragma unroll
    for (int i = 0; i < 2; ++i)
#pragma unroll
        for (int j = 0; j < 4; ++j)
#pragma unroll
            for (int r = 0; r < 4; ++r)
                C[(size_t)(m0 + wm * 32 + i * 16 + lg * 4 + r) * ldc +
                  n0 + wn * 64 + j * 16 + lr] = acc[i][j][r];
}

// ---------- RoPE from qkv f32 -> Qb/Kb bf16
__global__ void rope_conv(const float* __restrict__ qkv, const float* __restrict__ cosb,
                          const float* __restrict__ sinb, unsigned short* __restrict__ Qb,
                          unsigned short* __restrict__ Kb) {
    int idx = blockIdx.x * 256 + threadIdx.x;
    int d = idx & 31;
    int head = (idx >> 5) % 40;
    int s = idx / (32 * 40);
    if (s >= S_LEN) return;
    float c1 = cosb[s * HD + d],      s1 = sinb[s * HD + d];
    float c2 = cosb[s * HD + d + 32], s2 = sinb[s * HD + d + 32];
    const float* p;
    unsigned short* o;
    if (head < NH) {
        p = qkv + (size_t)s * DQKV + head * HD + d;
        o = Qb + (size_t)s * HID + head * HD + d;
    } else {
        p = qkv + (size_t)s * DQKV + K_OFF + (head - NH) * HD + d;
        o = Kb + (size_t)s * 512 + (head - NH) * HD + d;
    }
    float x1 = p[0], x2 = p[32];
    o[0]  = f2bf(x1 * c1 - x2 * s1);
    o[32] = f2bf(x2 * c2 + x1 * s2);
}

// ---------- pair-balanced fused flash attention
// grid (8 pairs, 32 heads), block 512 (8 waves; even waves -> qt=p, odd -> qt=15-p)
__global__ __launch_bounds__(512, 2) void attn_fused(const unsigned short* __restrict__ Qb,
                                                     const unsigned short* __restrict__ Kb,
                                                     const unsigned short* __restrict__ Vt,
                                                     float* __restrict__ w,
                                                     unsigned short* __restrict__ Ab) {
    __shared__ __align__(16) unsigned short Ks[128 * 72];    // [k][d]
    __shared__ __align__(16) unsigned short Vs[64 * 136];    // [d][k]
    __shared__ __align__(16) unsigned short Ps[8][32 * 40];  // per-wave P k-slice
    const int p = blockIdx.x, h = blockIdx.y, kvh = h >> 2;
    const int t = threadIdx.x, lane = t & 63, wv = t >> 6;
    const int grp = wv & 1, wr = wv >> 1;
    const int qt = grp ? (15 - p) : p;
    const int q0 = qt * 128;
    const int lr = lane & 15, lg = lane >> 4;
    const int ktmax = 15 - p;
    unsigned short* Pw = &Ps[wv][0];

    // Q fragments (B-operand): rows q0 + wr*32 + i*16 + lr
    short8 qf[2][2];
#pragma unroll
    for (int i = 0; i < 2; ++i)
#pragma unroll
        for (int kk = 0; kk < 2; ++kk)
            qf[i][kk] = *(const short8*)&Qb[(size_t)(q0 + wr * 32 + i * 16 + lr) * HID +
                                            h * HD + kk * 32 + lg * 8];

    const int krow = t >> 2, kc = (t & 3) * 16;
    const int vrow = t >> 3, vc = (t & 7) * 16;

    float m_r[2] = {-3.0e38f, -3.0e38f};
    float l_r[2] = {0.f, 0.f};

    // ================= pass 1: row max + row sum =================
    for (int kt = 0; kt <= ktmax; ++kt) {
        __syncthreads();
        *(short8*)&Ks[krow * 72 + kc] =
            *(const short8*)&Kb[(size_t)(kt * 128 + krow) * 512 + kvh * HD + kc];
        *(short8*)&Ks[krow * 72 + kc + 8] =
            *(const short8*)&Kb[(size_t)(kt * 128 + krow) * 512 + kvh * HD + kc + 8];
        __syncthreads();
        if (kt > qt) continue;
        f32x4 acc[8][2] = {};
#pragma unroll
        for (int kk = 0; kk < 2; ++kk) {
            short8 af[8];
#pragma unroll
            for (int j = 0; j < 8; ++j)
                af[j] = *(const short8*)&Ks[(j * 16 + lr) * 72 + kk * 32 + lg * 8];
#pragma unroll
            for (int j = 0; j < 8; ++j)
#pragma unroll
                for (int i = 0; i < 2; ++i)
                    acc[j][i] = __builtin_amdgcn_mfma_f32_16x16x32_bf16(af[j], qf[i][kk], acc[j][i], 0, 0, 0);
        }
        const bool diag = (kt == qt);
#pragma unroll
        for (int i = 0; i < 2; ++i) {
            const int qg = q0 + wr * 32 + i * 16 + lr;
            float tm = -3.0e38f;
#pragma unroll
            for (int j = 0; j < 8; ++j)
#pragma unroll
                for (int r = 0; r < 4; ++r) {
                    int kg = kt * 128 + j * 16 + lg * 4 + r;
                    float s = acc[j][i][r] * SCALE;
                    s = (!diag || kg <= qg) ? s : -1.0e30f;
                    acc[j][i][r] = s;
                    tm = fmaxf(tm, s);
                }
            tm = fmaxf(tm, __shfl_xor(tm, 16));
            tm = fmaxf(tm, __shfl_xor(tm, 32));
            float mn = fmaxf(m_r[i], tm);
            float sum = 0.f;
#pragma unroll
            for (int j = 0; j < 8; ++j)
#pragma unroll
                for (int r = 0; r < 4; ++r)
                    sum += __expf(acc[j][i][r] - mn);
            sum += __shfl_xor(sum, 16);
            sum += __shfl_xor(sum, 32);
            l_r[i] = l_r[i] * __expf(m_r[i] - mn) + sum;
            m_r[i] = mn;
        }
    }

    const float invl[2] = {1.f / l_r[0], 1.f / l_r[1]};

    // ================= pass 2: weights write + PV =================
    f32x4 o[2][4] = {};
    for (int kt = 0; kt <= ktmax; ++kt) {
        __syncthreads();
        *(short8*)&Ks[krow * 72 + kc] =
            *(const short8*)&Kb[(size_t)(kt * 128 + krow) * 512 + kvh * HD + kc];
        *(short8*)&Ks[krow * 72 + kc + 8] =
            *(const short8*)&Kb[(size_t)(kt * 128 + krow) * 512 + kvh * HD + kc + 8];
        *(short8*)&Vs[vrow * 136 + vc] =
            *(const short8*)&Vt[(size_t)(kvh * HD + vrow) * S_LEN + kt * 128 + vc];
        *(short8*)&Vs[vrow * 136 + vc + 8] =
            *(const short8*)&Vt[(size_t)(kvh * HD + vrow) * S_LEN + kt * 128 + vc + 8];
        __syncthreads();
        if (kt <= qt) {
            f32x4 acc[8][2] = {};
#pragma unroll
            for (int kk = 0; kk < 2; ++kk) {
                short8 af[8];
#pragma unroll
                for (int j = 0; j < 8; ++j)
                    af[j] = *(const short8*)&Ks[(j * 16 + lr) * 72 + kk * 32 + lg * 8];
#pragma unroll
                for (int j = 0; j < 8; ++j)
#pragma unroll
                    for (int i = 0; i < 2; ++i)
                        acc[j][i] = __builtin_amdgcn_mfma_f32_16x16x32_bf16(af[j], qf[i][kk], acc[j][i], 0, 0, 0);
            }
            const bool diag = (kt == qt);
#pragma unroll
            for (int ks = 0; ks < 4; ++ks) {
                // softmax-normalize this 32-k slice into per-wave Ps
#pragma unroll
                for (int i = 0; i < 2; ++i) {
                    const int qg = q0 + wr * 32 + i * 16 + lr;
#pragma unroll
                    for (int jj = 0; jj < 2; ++jj) {
                        const int j = ks * 2 + jj;
                        ushort4 pk;
#pragma unroll
                        for (int r = 0; r < 4; ++r) {
                            int kg = kt * 128 + j * 16 + lg * 4 + r;
                            float s = acc[j][i][r] * SCALE;
                            s = (!diag || kg <= qg) ? s : -1.0e30f;
                            ((unsigned short*)&pk)[r] = f2bf(__expf(s - m_r[i]) * invl[i]);
                        }
                        *(ushort4*)&Pw[(i * 16 + lr) * 40 + jj * 16 + lg * 4] = pk;
                    }
                }
                // PV for this slice
                short8 pa[2], vb[4];
#pragma unroll
                for (int i = 0; i < 2; ++i)
                    pa[i] = *(const short8*)&Pw[(i * 16 + lr) * 40 + lg * 8];
#pragma unroll
                for (int j2 = 0; j2 < 4; ++j2)
                    vb[j2] = *(const short8*)&Vs[(j2 * 16 + lr) * 136 + ks * 32 + lg * 8];
#pragma unroll
                for (int i = 0; i < 2; ++i)
#pragma unroll
                    for (int j2 = 0; j2 < 4; ++j2)
                        o[i][j2] = __builtin_amdgcn_mfma_f32_16x16x32_bf16(pa[i], vb[j2], o[i][j2], 0, 0, 0);
                // weights global write for this slice
#pragma unroll
                for (int rp = 0; rp < 2; ++rp) {
                    int rq = (lane >> 2) + rp * 16;
                    int cb = (lane & 3) * 8;
                    short8 pv8 = *(const short8*)&Pw[rq * 40 + cb];
                    float4 f0 = {bf2f((unsigned short)pv8[0]), bf2f((unsigned short)pv8[1]),
                                 bf2f((unsigned short)pv8[2]), bf2f((unsigned short)pv8[3])};
                    float4 f1 = {bf2f((unsigned short)pv8[4]), bf2f((unsigned short)pv8[5]),
                                 bf2f((unsigned short)pv8[6]), bf2f((unsigned short)pv8[7])};
                    size_t base = ((size_t)h * S_LEN + q0 + wr * 32 + rq) * S_LEN + kt * 128 + ks * 32 + cb;
                    *(float4*)&w[base] = f0;
                    *(float4*)&w[base + 4] = f1;
                }
            }
        } else {
            float4 z4 = {0.f, 0.f, 0.f, 0.f};
#pragma unroll
            for (int rr = 0; rr < 16; ++rr) {
                int row = wr * 32 + rr * 2 + (lane >> 5);
                *(float4*)&w[((size_t)h * S_LEN + q0 + row) * S_LEN + kt * 128 + (lane & 31) * 4] = z4;
            }
        }
    }
    // remaining upper zero tiles (both groups: kt = 16-p .. 15)
    for (int kt = ktmax + 1; kt < 16; ++kt) {
        float4 z4 = {0.f, 0.f, 0.f, 0.f};
#pragma unroll
        for (int rr = 0; rr < 16; ++rr) {
            int row = wr * 32 + rr * 2 + (lane >> 5);
            *(float4*)&w[((size_t)h * S_LEN + q0 + row) * S_LEN + kt * 128 + (lane & 31) * 4] = z4;
        }
    }
    // attn output (bf16)
#pragma unroll
    for (int i = 0; i < 2; ++i)
#pragma unroll
        for (int j2 = 0; j2 < 4; ++j2)
#pragma unroll
            for (int r = 0; r < 4; ++r)
                Ab[(size_t)(q0 + wr * 32 + i * 16 + lg * 4 + r) * HID +
                   h * HD + j2 * 16 + lr] = f2bf(o[i][j2][r]);
}

extern "C" void kernel_launch(void* const* d_in, const int* in_sizes, int n_in,
                              void* d_out, int out_size, void* d_ws, size_t ws_size,
                              hipStream_t stream) {
    const float* hidden = (const float*)d_in[0];
    const float* cosb   = (const float*)d_in[1];
    const float* sinb   = (const float*)d_in[2];
    const float* Wq     = (const float*)d_in[3];
    const float* Wk     = (const float*)d_in[4];
    const float* Wv     = (const float*)d_in[5];
    const float* Wo     = (const float*)d_in[6];

    float* out_mat = (float*)d_out;                              // S x HID
    float* weights = (float*)d_out + (size_t)S_LEN * HID;        // NH x S x S

    char* wsb = (char*)d_ws;
    float* qkv          = (float*)wsb;                                        // 24 MB
    unsigned short* Wt  = (unsigned short*)(wsb + (size_t)24 * 1024 * 1024);  // 12 MB
    unsigned short* Wot = (unsigned short*)(wsb + (size_t)36 * 1024 * 1024);  // 8 MB
    unsigned short* Qb  = (unsigned short*)(wsb + (size_t)44 * 1024 * 1024);  // 8 MB
    unsigned short* Kb  = (unsigned short*)(wsb + (size_t)52 * 1024 * 1024);  // 2 MB
    unsigned short* Vt  = (unsigned short*)(wsb + (size_t)54 * 1024 * 1024);  // 2 MB
    unsigned short* Hb  = (unsigned short*)(wsb + (size_t)56 * 1024 * 1024);  // 8 MB
    unsigned short* Ab  = Hb;  // alias: Hb dead after QKV GEMM

    // 1) prep: weight transposes + hidden conversion (one launch)
    prep<<<dim3(64, 64, 5), 256, 0, stream>>>(Wq, Wk, Wv, Wo, hidden, Wt, Wot, Hb);

    // 2) fused QKV projection
    gemm_m97<<<dim3(DQKV / 128, S_LEN / 128), 512, 0, stream>>>(Hb, Wt, qkv, HID, HID, HID, DQKV);

    // 3) RoPE -> Qb/Kb bf16; V -> Vt (transposed bf16)
    rope_conv<<<(S_LEN * 40 * 32) / 256, 256, 0, stream>>>(qkv, cosb, sinb, Qb, Kb);
    tconv<<<dim3(16, 64), 256, 0, stream>>>(qkv + V_OFF, DQKV, Vt, S_LEN);

    // 4) pair-balanced fused attention: weights (f32) + attn (bf16)
    attn_fused<<<dim3(8, NH), 512, 0, stream>>>(Qb, Kb, Vt, weights, Ab);

    // 5) output projection
    gemm_m97<<<dim3(HID / 128, S_LEN / 128), 512, 0, stream>>>(Ab, Wot, out_mat, HID, HID, HID, HID);
}